// Round 19
// baseline (57.643 us; speedup 1.0000x reference)
//
#include <hip/hip_runtime.h>
#include <hip/hip_bf16.h>

#define TSEQ 2048
#define DH   64
#define NBH  32      // B*H
#define KT   64      // k rows per tile per stream
#define NIT  16      // (TSEQ/2)/KT iterations per stream

typedef __attribute__((ext_vector_type(8)))  short short8_t;
typedef __attribute__((ext_vector_type(16))) float f32x16;
typedef __attribute__((ext_vector_type(4)))  unsigned short ushort4_t;

#define LOG2E 1.44269504088896340736f
#define MSUB  12.0f   // static softmax max (log2 domain); |scores*log2e| bounded ~9

__device__ __forceinline__ unsigned short f2bf(float f) {
    unsigned int u = __float_as_uint(f);
    return (unsigned short)((u + 0x7fffu + ((u >> 16) & 1u)) >> 16);
}

__device__ __forceinline__ unsigned int cvtpk(float lo, float hi) {
    unsigned int r;
    asm("v_cvt_pk_bf16_f32 %0, %1, %2" : "=v"(r) : "v"(lo), "v"(hi));
    return r;
}

// fast exp2: compiler intrinsic (backend handles TRANS hazards) or libm fallback.
// NEVER raw inline-asm v_exp_f32 (R9 lesson: TRANS hazard invisible to compiler).
__device__ __forceinline__ float exp2r(float x) {
#if __has_builtin(__builtin_amdgcn_exp2f)
    return __builtin_amdgcn_exp2f(x);
#else
    return exp2f(x);
#endif
}

#define GL2L16(g, l) __builtin_amdgcn_global_load_lds( \
    (__attribute__((address_space(1))) void*)(void*)(g), \
    (__attribute__((address_space(3))) void*)(l), 16, 0, 0)

// 128B-row tiles (K and V both at KT=64): slot = row&7  (R4-R18-verified)
__device__ __forceinline__ unsigned int kswz(unsigned int row, unsigned int cb) {
    return row * 128u + (cb ^ ((row & 7u) << 4));
}

// fused prep: blocks [0,2048) convert K fp32->bf16; blocks [2048,3072) transpose V
__global__ __launch_bounds__(256) void prep_kernel(const float* __restrict__ K,
                                                   unsigned short* __restrict__ Kb,
                                                   const float* __restrict__ V,
                                                   unsigned short* __restrict__ Vt) {
    __shared__ float tile[64][65];
    const int tid = threadIdx.x;
    if (blockIdx.x < 2048) {
        int i = blockIdx.x * 256 + tid;
        const float4* s = reinterpret_cast<const float4*>(K) + (size_t)i * 2;
        float4 a = s[0], b = s[1];
        short8_t o;
        o[0] = (short)f2bf(a.x); o[1] = (short)f2bf(a.y);
        o[2] = (short)f2bf(a.z); o[3] = (short)f2bf(a.w);
        o[4] = (short)f2bf(b.x); o[5] = (short)f2bf(b.y);
        o[6] = (short)f2bf(b.z); o[7] = (short)f2bf(b.w);
        *reinterpret_cast<short8_t*>(Kb + (size_t)i * 8) = o;
        return;
    }
    const int vbid = blockIdx.x - 2048;
    const int bh = vbid >> 5;
    const int t0 = (vbid & 31) * 64;
    const float* src = V + ((size_t)bh * TSEQ + t0) * DH;
#pragma unroll
    for (int it = 0; it < 4; ++it) {
        int idx = tid + it * 256;
        int row = idx >> 4;
        int c   = (idx & 15) * 4;
        float4 v = *reinterpret_cast<const float4*>(src + row * DH + c);
        tile[row][c + 0] = v.x; tile[row][c + 1] = v.y;
        tile[row][c + 2] = v.z; tile[row][c + 3] = v.w;
    }
    __syncthreads();
#pragma unroll
    for (int it = 0; it < 4; ++it) {
        int idx = tid + it * 256;
        int d  = idx >> 4;
        int c  = (idx & 15) * 4;
        ushort4_t o;
        o[0] = f2bf(tile[c + 0][d]); o[1] = f2bf(tile[c + 1][d]);
        o[2] = f2bf(tile[c + 2][d]); o[3] = f2bf(tile[c + 3][d]);
        *reinterpret_cast<ushort4_t*>(Vt + ((size_t)bh * DH + d) * TSEQ + t0 + c) = o;
    }
}

// Flash attention: R18 skeleton (KT=64, 16 rounds, vmcnt(8) 2-deep staging)
// with the two 32k-subtiles FUSED into one interleaved body: 4 independent QK
// chains + 64 independent exps + 4 PV chains per pinned region -> intra-wave
// ILP so MFMA/TRANS/LDS pipes overlap (R18 showed them serialized, 96% sum).
// VGPR grows into the 128-256 tier, which is free: LDS (72KB) already caps
// occupancy at 2 blocks/CU.
__global__ __launch_bounds__(256, 2) void attn_kernel(const float* __restrict__ Qf,
                                                      const unsigned short* __restrict__ Kb,
                                                      const unsigned short* __restrict__ Vt,
                                                      const float* __restrict__ mask,
                                                      float* __restrict__ out) {
    // buf0 @0, buf1 @32K (each: K s0 0-8K | K s1 8-16K | V s0 16-24K | V s1 24-32K)
    // mask f32 @64K..72K
    __shared__ char lds[73728];
    float* smsk = reinterpret_cast<float*>(lds + 65536);

    const int tid  = threadIdx.x;
    const int wave = tid >> 6;
    const int lane = tid & 63;
    const int l31  = lane & 31;
    const int hi   = lane >> 5;
    const int s    = wave >> 1;    // k-stream
    const int qw   = wave & 1;     // q-wave (64 rows)

    // bijective XCD swizzle (512 blocks % 8 == 0): 4 bh per XCD
    const int bid = blockIdx.x;
    const int bh  = (bid & 7) * 4 + (bid >> 7);
    const int qb  = (bid >> 3) & 15;
    const int q0  = qb * 128 + qw * 64;
    const int b   = bh >> 4;

    // staging: 32 segs x 1KB per buffer (R18-verified map)
    const char* gKc = reinterpret_cast<const char*>(Kb + (size_t)bh * TSEQ * DH);
    const char* gVc = reinterpret_cast<const char*>(Vt + (size_t)bh * DH * TSEQ);
    const unsigned int rA  = wave * 8 + (lane >> 3);        // rows 0..31
    const unsigned int rB  = rA + 32;                       // rows 32..63
    const unsigned int cb  = (lane & 7) * 16;
    const unsigned int scb = cb ^ (((lane >> 3) & 7u) << 4);
    const char* pk0a = gKc + (size_t)rA * 128 + scb;
    const char* pk0b = gKc + (size_t)rB * 128 + scb;
    const char* pk1a = pk0a + (size_t)1024 * 128;
    const char* pk1b = pk0b + (size_t)1024 * 128;
    const char* pv0a = gVc + (size_t)rA * 4096 + scb;
    const char* pv0b = gVc + (size_t)rB * 4096 + scb;
    const char* pv1a = pv0a + (size_t)1024 * 2;
    const char* pv1b = pv0b + (size_t)1024 * 2;
    const unsigned int lko0a = (wave +  0) * 1024 + lane * 16;
    const unsigned int lko0b = (wave +  4) * 1024 + lane * 16;
    const unsigned int lko1a = (wave +  8) * 1024 + lane * 16;
    const unsigned int lko1b = (wave + 12) * 1024 + lane * 16;
    const unsigned int lvo0a = (wave + 16) * 1024 + lane * 16;
    const unsigned int lvo0b = (wave + 20) * 1024 + lane * 16;
    const unsigned int lvo1a = (wave + 24) * 1024 + lane * 16;
    const unsigned int lvo1b = (wave + 28) * 1024 + lane * 16;

    auto stage = [&](int buf) {
        char* base = lds + buf * 32768;
        GL2L16(pk0a, base + lko0a);
        GL2L16(pk0b, base + lko0b);
        GL2L16(pk1a, base + lko1a);
        GL2L16(pk1b, base + lko1b);
        GL2L16(pv0a, base + lvo0a);
        GL2L16(pv0b, base + lvo0b);
        GL2L16(pv1a, base + lvo1a);
        GL2L16(pv1b, base + lvo1b);
        pk0a += KT * 128; pk0b += KT * 128; pk1a += KT * 128; pk1b += KT * 128;
        pv0a += KT * 2;   pv0b += KT * 2;   pv1a += KT * 2;   pv1b += KT * 2;
    };

    // prologue: tiles 0 -> buf0, 1 -> buf1
    stage(0);
    stage(1);

    // stage mask row: *log2e - MSUB
    {
        const float4* m4 = reinterpret_cast<const float4*>(mask + (size_t)b * TSEQ);
        float4* s4 = reinterpret_cast<float4*>(smsk);
#pragma unroll
        for (int i = 0; i < 2; ++i) {
            int idx = tid + i * 256;
            float4 v = m4[idx];
            float4 w;
            w.x = v.x * LOG2E - MSUB; w.y = v.y * LOG2E - MSUB;
            w.z = v.z * LOG2E - MSUB; w.w = v.w * LOG2E - MSUB;
            s4[idx] = w;
        }
    }

    // Q B-frags (2 q-sets) from fp32 global, scale*log2e folded [R7-R18-verified]
    const float QS = 0.125f * LOG2E;
    short8_t qfA[4], qfB[4];
#pragma unroll
    for (int qs = 0; qs < 2; ++qs) {
        const float* qrow = Qf + ((size_t)bh * TSEQ + q0 + qs * 32 + l31) * DH;
#pragma unroll
        for (int dc = 0; dc < 4; ++dc) {
            float4 v0 = *reinterpret_cast<const float4*>(qrow + 16 * dc + 8 * hi);
            float4 v1 = *reinterpret_cast<const float4*>(qrow + 16 * dc + 8 * hi + 4);
            union { unsigned int u[4]; short8_t s8; } pk;
            pk.u[0] = cvtpk(v0.x * QS, v0.y * QS);
            pk.u[1] = cvtpk(v0.z * QS, v0.w * QS);
            pk.u[2] = cvtpk(v1.x * QS, v1.y * QS);
            pk.u[3] = cvtpk(v1.z * QS, v1.w * QS);
            if (qs == 0) qfA[dc] = pk.s8; else qfB[dc] = pk.s8;
        }
    }

    f32x16 oA0, oA1, oB0, oB1;
#pragma unroll
    for (int r = 0; r < 16; ++r) { oA0[r] = 0.f; oA1[r] = 0.f; oB0[r] = 0.f; oB1[r] = 0.f; }
    float lA = 0.f, lB = 0.f;

    const int kofs = s * 1024;

    // fused round body: both 32k subtiles interleaved for intra-wave ILP
    auto do_round = [&](const char* bb, int it) {
        const char* cK = bb + s * 8192;
        const char* cV = bb + 16384 + s * 8192;

        // K A-frags, both subtiles (8 reads)
        short8_t k0f0 = *reinterpret_cast<const short8_t*>(cK + kswz(l31,      16 * hi));
        short8_t k0f1 = *reinterpret_cast<const short8_t*>(cK + kswz(l31,      32 + 16 * hi));
        short8_t k0f2 = *reinterpret_cast<const short8_t*>(cK + kswz(l31,      64 + 16 * hi));
        short8_t k0f3 = *reinterpret_cast<const short8_t*>(cK + kswz(l31,      96 + 16 * hi));
        short8_t k1f0 = *reinterpret_cast<const short8_t*>(cK + kswz(32 + l31, 16 * hi));
        short8_t k1f1 = *reinterpret_cast<const short8_t*>(cK + kswz(32 + l31, 32 + 16 * hi));
        short8_t k1f2 = *reinterpret_cast<const short8_t*>(cK + kswz(32 + l31, 64 + 16 * hi));
        short8_t k1f3 = *reinterpret_cast<const short8_t*>(cK + kswz(32 + l31, 96 + 16 * hi));

        // C-init from mask, both subtiles
        const float* mb0 = &smsk[kofs + it * KT + 4 * hi];
        const float* mb1 = mb0 + 32;
        f32x16 scA0, scB0, scA1, scB1;
        {
            float4 m0 = *reinterpret_cast<const float4*>(mb0);
            float4 m1 = *reinterpret_cast<const float4*>(mb0 + 8);
            float4 m2 = *reinterpret_cast<const float4*>(mb0 + 16);
            float4 m3 = *reinterpret_cast<const float4*>(mb0 + 24);
            scA0[0]  = m0.x; scA0[1]  = m0.y; scA0[2]  = m0.z; scA0[3]  = m0.w;
            scA0[4]  = m1.x; scA0[5]  = m1.y; scA0[6]  = m1.z; scA0[7]  = m1.w;
            scA0[8]  = m2.x; scA0[9]  = m2.y; scA0[10] = m2.z; scA0[11] = m2.w;
            scA0[12] = m3.x; scA0[13] = m3.y; scA0[14] = m3.z; scA0[15] = m3.w;
        }
        scB0 = scA0;
        {
            float4 m0 = *reinterpret_cast<const float4*>(mb1);
            float4 m1 = *reinterpret_cast<const float4*>(mb1 + 8);
            float4 m2 = *reinterpret_cast<const float4*>(mb1 + 16);
            float4 m3 = *reinterpret_cast<const float4*>(mb1 + 24);
            scA1[0]  = m0.x; scA1[1]  = m0.y; scA1[2]  = m0.z; scA1[3]  = m0.w;
            scA1[4]  = m1.x; scA1[5]  = m1.y; scA1[6]  = m1.z; scA1[7]  = m1.w;
            scA1[8]  = m2.x; scA1[9]  = m2.y; scA1[10] = m2.z; scA1[11] = m2.w;
            scA1[12] = m3.x; scA1[13] = m3.y; scA1[14] = m3.z; scA1[15] = m3.w;
        }
        scB1 = scA1;

        // QK: 16 MFMAs, 4 independent chains interleaved
        __builtin_amdgcn_s_setprio(1);
        scA0 = __builtin_amdgcn_mfma_f32_32x32x16_bf16(k0f0, qfA[0], scA0, 0, 0, 0);
        scB0 = __builtin_amdgcn_mfma_f32_32x32x16_bf16(k0f0, qfB[0], scB0, 0, 0, 0);
        scA1 = __builtin_amdgcn_mfma_f32_32x32x16_bf16(k1f0, qfA[0], scA1, 0, 0, 0);
        scB1 = __builtin_amdgcn_mfma_f32_32x32x16_bf16(k1f0, qfB[0], scB1, 0, 0, 0);
        scA0 = __builtin_amdgcn_mfma_f32_32x32x16_bf16(k0f1, qfA[1], scA0, 0, 0, 0);
        scB0 = __builtin_amdgcn_mfma_f32_32x32x16_bf16(k0f1, qfB[1], scB0, 0, 0, 0);
        scA1 = __builtin_amdgcn_mfma_f32_32x32x16_bf16(k1f1, qfA[1], scA1, 0, 0, 0);
        scB1 = __builtin_amdgcn_mfma_f32_32x32x16_bf16(k1f1, qfB[1], scB1, 0, 0, 0);
        scA0 = __builtin_amdgcn_mfma_f32_32x32x16_bf16(k0f2, qfA[2], scA0, 0, 0, 0);
        scB0 = __builtin_amdgcn_mfma_f32_32x32x16_bf16(k0f2, qfB[2], scB0, 0, 0, 0);
        scA1 = __builtin_amdgcn_mfma_f32_32x32x16_bf16(k1f2, qfA[2], scA1, 0, 0, 0);
        scB1 = __builtin_amdgcn_mfma_f32_32x32x16_bf16(k1f2, qfB[2], scB1, 0, 0, 0);
        scA0 = __builtin_amdgcn_mfma_f32_32x32x16_bf16(k0f3, qfA[3], scA0, 0, 0, 0);
        scB0 = __builtin_amdgcn_mfma_f32_32x32x16_bf16(k0f3, qfB[3], scB0, 0, 0, 0);
        scA1 = __builtin_amdgcn_mfma_f32_32x32x16_bf16(k1f3, qfA[3], scA1, 0, 0, 0);
        scB1 = __builtin_amdgcn_mfma_f32_32x32x16_bf16(k1f3, qfB[3], scB1, 0, 0, 0);
        __builtin_amdgcn_s_setprio(0);

        // V A-frags, both subtiles (8 reads)
        short8_t v0f00 = *reinterpret_cast<const short8_t*>(cV + kswz(l31,      16 * hi));
        short8_t v0f01 = *reinterpret_cast<const short8_t*>(cV + kswz(32 + l31, 16 * hi));
        short8_t v0f10 = *reinterpret_cast<const short8_t*>(cV + kswz(l31,      32 + 16 * hi));
        short8_t v0f11 = *reinterpret_cast<const short8_t*>(cV + kswz(32 + l31, 32 + 16 * hi));
        short8_t v1f00 = *reinterpret_cast<const short8_t*>(cV + kswz(l31,      64 + 16 * hi));
        short8_t v1f01 = *reinterpret_cast<const short8_t*>(cV + kswz(32 + l31, 64 + 16 * hi));
        short8_t v1f10 = *reinterpret_cast<const short8_t*>(cV + kswz(l31,      96 + 16 * hi));
        short8_t v1f11 = *reinterpret_cast<const short8_t*>(cV + kswz(32 + l31, 96 + 16 * hi));

        // softmax+pack+PV, both subtiles interleaved per c-half
#pragma unroll
        for (int c = 0; c < 2; ++c) {
            unsigned int a00, a01, a02, a03, b00, b01, b02, b03;
            unsigned int a10, a11, a12, a13, b10, b11, b12, b13;
            {
                float e0 = exp2r(scA0[8*c+0]), e1 = exp2r(scA0[8*c+1]);
                float e2 = exp2r(scA0[8*c+2]), e3 = exp2r(scA0[8*c+3]);
                float e4 = exp2r(scA0[8*c+4]), e5 = exp2r(scA0[8*c+5]);
                float e6 = exp2r(scA0[8*c+6]), e7 = exp2r(scA0[8*c+7]);
                lA += ((e0+e1)+(e2+e3)) + ((e4+e5)+(e6+e7));
                a00 = cvtpk(e0, e1); a02 = cvtpk(e2, e3);
                a01 = cvtpk(e4, e5); a03 = cvtpk(e6, e7);
            }
            {
                float e0 = exp2r(scB0[8*c+0]), e1 = exp2r(scB0[8*c+1]);
                float e2 = exp2r(scB0[8*c+2]), e3 = exp2r(scB0[8*c+3]);
                float e4 = exp2r(scB0[8*c+4]), e5 = exp2r(scB0[8*c+5]);
                float e6 = exp2r(scB0[8*c+6]), e7 = exp2r(scB0[8*c+7]);
                lB += ((e0+e1)+(e2+e3)) + ((e4+e5)+(e6+e7));
                b00 = cvtpk(e0, e1); b02 = cvtpk(e2, e3);
                b01 = cvtpk(e4, e5); b03 = cvtpk(e6, e7);
            }
            {
                float e0 = exp2r(scA1[8*c+0]), e1 = exp2r(scA1[8*c+1]);
                float e2 = exp2r(scA1[8*c+2]), e3 = exp2r(scA1[8*c+3]);
                float e4 = exp2r(scA1[8*c+4]), e5 = exp2r(scA1[8*c+5]);
                float e6 = exp2r(scA1[8*c+6]), e7 = exp2r(scA1[8*c+7]);
                lA += ((e0+e1)+(e2+e3)) + ((e4+e5)+(e6+e7));
                a10 = cvtpk(e0, e1); a12 = cvtpk(e2, e3);
                a11 = cvtpk(e4, e5); a13 = cvtpk(e6, e7);
            }
            {
                float e0 = exp2r(scB1[8*c+0]), e1 = exp2r(scB1[8*c+1]);
                float e2 = exp2r(scB1[8*c+2]), e3 = exp2r(scB1[8*c+3]);
                float e4 = exp2r(scB1[8*c+4]), e5 = exp2r(scB1[8*c+5]);
                float e6 = exp2r(scB1[8*c+6]), e7 = exp2r(scB1[8*c+7]);
                lB += ((e0+e1)+(e2+e3)) + ((e4+e5)+(e6+e7));
                b10 = cvtpk(e0, e1); b12 = cvtpk(e2, e3);
                b11 = cvtpk(e4, e5); b13 = cvtpk(e6, e7);
            }
            asm("v_permlane32_swap_b32 %0, %1" : "+v"(a00), "+v"(a01));
            asm("v_permlane32_swap_b32 %0, %1" : "+v"(a02), "+v"(a03));
            asm("v_permlane32_swap_b32 %0, %1" : "+v"(b00), "+v"(b01));
            asm("v_permlane32_swap_b32 %0, %1" : "+v"(b02), "+v"(b03));
            asm("v_permlane32_swap_b32 %0, %1" : "+v"(a10), "+v"(a11));
            asm("v_permlane32_swap_b32 %0, %1" : "+v"(a12), "+v"(a13));
            asm("v_permlane32_swap_b32 %0, %1" : "+v"(b10), "+v"(b11));
            asm("v_permlane32_swap_b32 %0, %1" : "+v"(b12), "+v"(b13));
            union { unsigned int u[4]; short8_t s8; } pA0, pB0, pA1, pB1;
            pA0.u[0] = a00; pA0.u[1] = a02; pA0.u[2] = a01; pA0.u[3] = a03;
            pB0.u[0] = b00; pB0.u[1] = b02; pB0.u[2] = b01; pB0.u[3] = b03;
            pA1.u[0] = a10; pA1.u[1] = a12; pA1.u[2] = a11; pA1.u[3] = a13;
            pB1.u[0] = b10; pB1.u[1] = b12; pB1.u[2] = b11; pB1.u[3] = b13;
            short8_t v0f0 = c ? v0f10 : v0f00;
            short8_t v0f1 = c ? v0f11 : v0f01;
            short8_t v1f0 = c ? v1f10 : v1f00;
            short8_t v1f1 = c ? v1f11 : v1f01;
            __builtin_amdgcn_s_setprio(1);
            oA0 = __builtin_amdgcn_mfma_f32_32x32x16_bf16(v0f0, pA0.s8, oA0, 0, 0, 0);
            oB0 = __builtin_amdgcn_mfma_f32_32x32x16_bf16(v0f0, pB0.s8, oB0, 0, 0, 0);
            oA1 = __builtin_amdgcn_mfma_f32_32x32x16_bf16(v0f1, pA0.s8, oA1, 0, 0, 0);
            oB1 = __builtin_amdgcn_mfma_f32_32x32x16_bf16(v0f1, pB0.s8, oB1, 0, 0, 0);
            oA0 = __builtin_amdgcn_mfma_f32_32x32x16_bf16(v1f0, pA1.s8, oA0, 0, 0, 0);
            oB0 = __builtin_amdgcn_mfma_f32_32x32x16_bf16(v1f0, pB1.s8, oB0, 0, 0, 0);
            oA1 = __builtin_amdgcn_mfma_f32_32x32x16_bf16(v1f1, pA1.s8, oA1, 0, 0, 0);
            oB1 = __builtin_amdgcn_mfma_f32_32x32x16_bf16(v1f1, pB1.s8, oB1, 0, 0, 0);
            __builtin_amdgcn_s_setprio(0);
        }
    };

    __syncthreads();   // mask + tiles 0,1 visible (full drain, one-time)

    // main loop: two-barrier rounds (R18 skeleton, vmcnt(8) 2-deep)
    for (int t = 0; t < NIT - 1; ++t) {
        asm volatile("s_waitcnt vmcnt(8)" ::: "memory");
        __builtin_amdgcn_s_barrier();
        __builtin_amdgcn_sched_barrier(0);
        do_round(lds + (t & 1) * 32768, t);
        __builtin_amdgcn_sched_barrier(0);
        __builtin_amdgcn_s_barrier();
        __builtin_amdgcn_sched_barrier(0);
        if (t < NIT - 2) stage(t & 1);
    }
    asm volatile("s_waitcnt vmcnt(0)" ::: "memory");
    __builtin_amdgcn_s_barrier();
    __builtin_amdgcn_sched_barrier(0);
    do_round(lds + ((NIT - 1) & 1) * 32768, NIT - 1);

    __syncthreads();   // LDS reusable for merge

    // split-K merge (R18-verified): stream-1 waves write O^T,l; stream-0 combine.
    float lAt = lA + __shfl_xor(lA, 32);
    float lBt = lB + __shfl_xor(lB, 32);
    if (s == 1) {
#pragma unroll
        for (int qs = 0; qs < 2; ++qs) {
            char* wp = lds + qw * 16384 + qs * 8192;
            const f32x16& o0 = qs ? oB0 : oA0;
            const f32x16& o1 = qs ? oB1 : oA1;
#pragma unroll
            for (int i = 0; i < 8; ++i) {
                float4 v;
                if (i < 4) { v.x = o0[4*i]; v.y = o0[4*i+1]; v.z = o0[4*i+2]; v.w = o0[4*i+3]; }
                else       { v.x = o1[4*(i-4)]; v.y = o1[4*(i-4)+1]; v.z = o1[4*(i-4)+2]; v.w = o1[4*(i-4)+3]; }
                *reinterpret_cast<float4*>(wp + lane * 128 + ((i * 16) ^ ((lane & 7u) << 4))) = v;
            }
        }
        if (hi == 0) {
            reinterpret_cast<float*>(lds + 65536 + (qw * 2 + 0) * 128)[l31] = lAt;
            reinterpret_cast<float*>(lds + 65536 + (qw * 2 + 1) * 128)[l31] = lBt;
        }
    }
    __syncthreads();
    if (s == 0) {
#pragma unroll
        for (int qs = 0; qs < 2; ++qs) {
            const char* rp = lds + qw * 16384 + qs * 8192;
            const f32x16& o0 = qs ? oB0 : oA0;
            const f32x16& o1 = qs ? oB1 : oA1;
            float lpart = qs ? lBt : lAt;
            float ltt = lpart + reinterpret_cast<const float*>(lds + 65536 + (qw * 2 + qs) * 128)[l31];
            float inv = 1.0f / ltt;
            float* orow = out + ((size_t)bh * TSEQ + q0 + qs * 32 + l31) * DH;
#pragma unroll
            for (int i = 0; i < 8; ++i) {
                float4 o = *reinterpret_cast<const float4*>(rp + lane * 128 + ((i * 16) ^ ((lane & 7u) << 4)));
                float4 v;
                if (i < 4) {
                    v.x = (o0[4*i]   + o.x) * inv; v.y = (o0[4*i+1] + o.y) * inv;
                    v.z = (o0[4*i+2] + o.z) * inv; v.w = (o0[4*i+3] + o.w) * inv;
                } else {
                    v.x = (o1[4*(i-4)]   + o.x) * inv; v.y = (o1[4*(i-4)+1] + o.y) * inv;
                    v.z = (o1[4*(i-4)+2] + o.z) * inv; v.w = (o1[4*(i-4)+3] + o.w) * inv;
                }
                const int db = i >> 2, rr = i & 3;
                *reinterpret_cast<float4*>(orow + 32 * db + 8 * rr + 4 * hi) = v;
            }
        }
    }
}

extern "C" void kernel_launch(void* const* d_in, const int* in_sizes, int n_in,
                              void* d_out, int out_size, void* d_ws, size_t ws_size,
                              hipStream_t stream) {
    const float* Q    = (const float*)d_in[0];
    const float* K    = (const float*)d_in[1];
    const float* V    = (const float*)d_in[2];
    const float* mask = (const float*)d_in[3];
    float* out = (float*)d_out;

    const size_t N = (size_t)NBH * TSEQ * DH;
    unsigned short* Kb = (unsigned short*)d_ws;   // 8 MB
    unsigned short* Vt = Kb + N;                  // 8 MB

    hipLaunchKernelGGL(prep_kernel, dim3(2048 + 1024), dim3(256), 0, stream, K, Kb, V, Vt);
    hipLaunchKernelGGL(attn_kernel, dim3(16 * NBH), dim3(256), 0, stream,
                       Q, Kb, Vt, mask, out);
}